// Round 8
// baseline (363.632 us; speedup 1.0000x reference)
//
#include <hip/hip_runtime.h>

typedef float f32x4 __attribute__((ext_vector_type(4)));
typedef __bf16 bf16x8 __attribute__((ext_vector_type(8)));
typedef unsigned int u32;

#define WTHR 0.001f

// ---------------- ws layout (bytes) ----------------
static constexpr size_t WS_A1   = 0;                       // ushort[8388608] bf16 bits, NHWC
static constexpr size_t WS_A2   = 16777216;                // ushort[8388608] NHWC
static constexpr size_t WS_OUT1 = 33554432;                // float[8388608], NCHW
static constexpr size_t WS_TW   = 67108864;                // ushort[2*589824], layout [off][cc][kk][co][32]
static constexpr size_t WS_TB   = 69468160;                // float[8*256]
static constexpr size_t WS_GN1  = 69476352;                // float[512]
static constexpr size_t WS_GN2  = 69478400;                // float[512]

// ---------------- GN stats body: EXACT numpy-fp32 pairwise (bit-exact; DO NOT TOUCH) ----------------
__device__ __forceinline__ void gn_stats_body(const float* __restrict__ x, float* __restrict__ mean,
                                              float* __restrict__ rstd, int bg, int t,
                                              float* red /*[4]*/, float* Mv /*[1]*/)
{
    int lane = t & 63, wv = t >> 6;
    const float4* A = reinterpret_cast<const float4*>(x + (size_t)bg * 32768 + (size_t)t * 128);

    float r0, r1, r2, r3, r4, r5, r6, r7;
    {
        float4 v0 = A[0], v1 = A[1];
        r0 = v0.x; r1 = v0.y; r2 = v0.z; r3 = v0.w;
        r4 = v1.x; r5 = v1.y; r6 = v1.z; r7 = v1.w;
        for (int i = 2; i < 32; i += 2) {
            float4 u0 = A[i], u1 = A[i + 1];
            r0 += u0.x; r1 += u0.y; r2 += u0.z; r3 += u0.w;
            r4 += u1.x; r5 += u1.y; r6 += u1.z; r7 += u1.w;
        }
    }
    float p = ((r0 + r1) + (r2 + r3)) + ((r4 + r5) + (r6 + r7));
    #pragma unroll
    for (int st = 1; st <= 32; st <<= 1) p = p + __shfl_down(p, st);
    if (lane == 0) red[wv] = p;
    __syncthreads();
    if (t == 0) *Mv = ((red[0] + red[1]) + (red[2] + red[3])) / 32768.0f;
    __syncthreads();
    float mn = *Mv;

    {
        float4 v0 = A[0], v1 = A[1];
        float d;
        d = v0.x - mn; r0 = __fmul_rn(d, d);
        d = v0.y - mn; r1 = __fmul_rn(d, d);
        d = v0.z - mn; r2 = __fmul_rn(d, d);
        d = v0.w - mn; r3 = __fmul_rn(d, d);
        d = v1.x - mn; r4 = __fmul_rn(d, d);
        d = v1.y - mn; r5 = __fmul_rn(d, d);
        d = v1.z - mn; r6 = __fmul_rn(d, d);
        d = v1.w - mn; r7 = __fmul_rn(d, d);
        for (int i = 2; i < 32; i += 2) {
            float4 u0 = A[i], u1 = A[i + 1];
            d = u0.x - mn; r0 = r0 + __fmul_rn(d, d);
            d = u0.y - mn; r1 = r1 + __fmul_rn(d, d);
            d = u0.z - mn; r2 = r2 + __fmul_rn(d, d);
            d = u0.w - mn; r3 = r3 + __fmul_rn(d, d);
            d = u1.x - mn; r4 = r4 + __fmul_rn(d, d);
            d = u1.y - mn; r5 = r5 + __fmul_rn(d, d);
            d = u1.z - mn; r6 = r6 + __fmul_rn(d, d);
            d = u1.w - mn; r7 = r7 + __fmul_rn(d, d);
        }
    }
    p = ((r0 + r1) + (r2 + r3)) + ((r4 + r5) + (r6 + r7));
    #pragma unroll
    for (int st = 1; st <= 32; st <<= 1) p = p + __shfl_down(p, st);
    if (lane == 0) red[wv] = p;
    __syncthreads();
    if (t == 0) {
        float var = ((red[0] + red[1]) + (red[2] + red[3])) / 32768.0f;
        mean[bg] = mn;
        rstd[bg] = __fdiv_rn(1.0f, __fsqrt_rn(var + 1e-5f));
    }
}

__global__ __launch_bounds__(256)
void k_gn_stats(const float* __restrict__ x, float* __restrict__ mean, float* __restrict__ rstd)
{
    __shared__ float red[4];
    __shared__ float Mv;
    gn_stats_body(x, mean, rstd, blockIdx.x, threadIdx.x, red, &Mv);
}

// ---------------- fused prep: [0,256)=GN1 stats | [256,768)=ternarize | [768,776)=time-bias ----------------
__global__ __launch_bounds__(256)
void k_prep(const float* __restrict__ x, float* __restrict__ mean, float* __restrict__ rstd,
            const float* __restrict__ W1, const float* __restrict__ W2, unsigned short* __restrict__ twT,
            const float* __restrict__ te, const float* __restrict__ Wt, const float* __restrict__ bt,
            float* __restrict__ tb)
{
    __shared__ union { struct { float red[4]; float Mv; } g; unsigned short Q[2304]; } sh;
    int blk = blockIdx.x;
    int t = threadIdx.x;
    if (blk < 256) {
        gn_stats_body(x, mean, rstd, blk, t, sh.g.red, &sh.g.Mv);
    } else if (blk < 768) {
        int bb = blk - 256;                  // 0..511
        int co = bb & 255;
        const float* src = ((bb & 256) ? W2 : W1) + (size_t)co * 2304;
        unsigned short* base = twT + (size_t)(bb >> 8) * 589824;
        #pragma unroll
        for (int i = 0; i < 9; ++i) {
            float w = src[t + (i << 8)];
            sh.Q[t + (i << 8)] = (w > WTHR) ? (unsigned short)0x3F80u
                               : ((w < -WTHR) ? (unsigned short)0xBF80u : (unsigned short)0u);
        }
        __syncthreads();
        #pragma unroll
        for (int i = 0; i < 9; ++i) {
            int oidx = t + (i << 8);         // 2304 outputs: off = oidx>>8, ci = oidx&255
            int off = oidx >> 8, ci = oidx & 255;
            size_t dst = (size_t)off * 65536 + (size_t)(ci >> 6) * 16384
                       + (size_t)((ci >> 5) & 1) * 8192 + (size_t)co * 32 + (ci & 31);
            base[dst] = sh.Q[ci * 9 + off];
        }
    } else {
        int b = blk - 768, co = t;
        const float* wrow = Wt + (size_t)co * 512;
        const float* trow = te + (size_t)b * 512;
        float acc = 0.f;
        for (int k = 0; k < 512; ++k) {
            float w = wrow[k];
            float tw = (w > WTHR) ? 1.f : ((w < -WTHR) ? -1.f : 0.f);
            acc = __fmaf_rn(fmaxf(trow[k], 0.f), tw, acc);
        }
        tb[(b << 8) + co] = acc + bt[co];
    }
}

// ---------------- norm + relu + quant: NCHW f32 -> NHWC bf16 bits; (w&7) 16B-slot XOR swizzle ----------------
__global__ __launch_bounds__(256)
void k_norm_quant(const float* __restrict__ x, const float* __restrict__ gamma, const float* __restrict__ beta,
                  const float* __restrict__ mean, const float* __restrict__ rstd,
                  const float* __restrict__ scale, unsigned short* __restrict__ a)
{
    int blk = blockIdx.x;            // 512 = b*64+h
    int b = blk >> 6, h = blk & 63;
    int tid = threadIdx.x;
    __shared__ unsigned short T[64 * 256];     // 32KB: [w][granule^ (w&7)]
    float s = fabsf(*scale);
    int w = tid & 63;
    int g0 = (tid >> 6) << 3;
    #pragma unroll
    for (int o = 0; o < 8; ++o) {
        int gc = g0 + o;                       // granule = c>>3, 0..31
        alignas(16) unsigned short r8[8];
        float mnv = mean[(b << 5) + gc], rsv = rstd[(b << 5) + gc];
        #pragma unroll
        for (int j = 0; j < 8; ++j) {
            int c = (gc << 3) + j;
            float xv = x[((size_t)((b << 8) + c) << 12) + (h << 6) + w];
            float y = __fmul_rn(xv - mnv, rsv);
            y = y * gamma[c] + beta[c];
            y = fmaxf(y, 0.f);
            r8[j] = (rintf(__fdiv_rn(y, s)) >= 1.0f) ? (unsigned short)0x3F80u : (unsigned short)0u;
        }
        int gs = gc ^ (w & 7);
        *reinterpret_cast<uint4*>(&T[(w << 8) + (gs << 3)]) = *reinterpret_cast<const uint4*>(r8);
    }
    __syncthreads();
    unsigned short* dst = a + ((size_t)blk << 14);
    #pragma unroll
    for (int j = 0; j < 8; ++j) {
        int e = (j << 11) + (tid << 3);        // element = w*256 + c
        int ww = e >> 8;
        int gs = (tid & 31) ^ (ww & 7);
        *reinterpret_cast<uint4*>(dst + e) = *reinterpret_cast<const uint4*>(&T[(ww << 8) + (gs << 3)]);
    }
}

// ---------------- conv 3x3, implicit GEMM, bf16 MFMA ----------------
// Grid 512=(b,h), XCD-swizzled (XCD k owns batch k). 4 waves; wave tile co=64 x w=64 (acc 4x4).
// Per kk-step: 4 ds_read_b128 (acts) + 4 coalesced 1KB wf loads (L2) -> 16 MFMA.
// LDS double-buffered staging via global_load_lds w16 (pre-swizzled source).
template<int O>
__global__ __launch_bounds__(256, 2)
void k_conv(const unsigned short* __restrict__ acts,   // NHWC bf16 bits [8][64][64][256]
            const unsigned short* __restrict__ twT,    // [9][4][2][256][32] bf16 bits
            const float* __restrict__ bias,            // [256]
            const float* __restrict__ tb,              // [8][256] (O==0)
            const float* __restrict__ scale,
            const float* __restrict__ resid,           // x NCHW (O==1)
            float* __restrict__ out)                   // NCHW f32
{
    int blk0 = blockIdx.x;
    int logical = ((blk0 & 7) << 6) + (blk0 >> 3);   // 512 blocks: XCD k -> batch k
    int b = logical >> 6, h = logical & 63;
    int tid = threadIdx.x;
    int lane = tid & 63, wv = tid >> 6;
    int l15 = lane & 15, l4 = lane >> 4;

    __shared__ unsigned short Ls[2 * 3 * 64 * 64];   // 2 x 24576 B

    f32x4 acc[4][4];
    #pragma unroll
    for (int i = 0; i < 4; ++i)
        #pragma unroll
        for (int j = 0; j < 4; ++j) acc[i][j] = (f32x4){0.f, 0.f, 0.f, 0.f};

    int lw = lane >> 3;
    int lc = (lane & 7) ^ lw;
    int cobase = wv << 6;

    auto stage = [&](int cc, int buf) {
        #pragma unroll
        for (int i = 0; i < 6; ++i) {
            int chunk = wv * 6 + i;                  // 0..23, 1KB each
            int dh = chunk >> 3;
            int w0 = (chunk & 7) << 3;
            int hh = h + dh - 1;
            char* ldst = (char*)Ls + buf * 24576 + chunk * 1024;
            if ((unsigned)hh < 64u) {
                const unsigned short* g = acts
                    + ((size_t)(((b << 6) + hh) << 6) + (w0 + lw)) * 256 + (cc << 6) + (lc << 3);
                __builtin_amdgcn_global_load_lds(
                    (const __attribute__((address_space(1))) u32*)g,
                    (__attribute__((address_space(3))) u32*)ldst, 16, 0, 0);
            } else {
                *reinterpret_cast<uint4*>(ldst + lane * 16) = (uint4){0u, 0u, 0u, 0u};
            }
        }
    };

    stage(0, 0);
    int cur = 0;
    for (int cc = 0; cc < 4; ++cc) {
        __syncthreads();                             // buf[cur] ready (drains prefetch)
        if (cc < 3) stage(cc + 1, cur ^ 1);          // issue next prefetch, no wait
        const char* Lb = (const char*)Ls + cur * 24576;

        #pragma unroll
        for (int off = 0; off < 9; ++off) {
            const int kh = off / 3;
            const int kw = off % 3 - 1;
            #pragma unroll
            for (int kk = 0; kk < 2; ++kk) {
                bf16x8 af[4], wf[4];
                #pragma unroll
                for (int nt = 0; nt < 4; ++nt) {
                    int wi = (nt << 4) + l15 + kw;
                    bool ok = (unsigned)wi < 64u;
                    int wc = ok ? wi : 0;
                    int byte = ((kh << 6) + wc) * 128 + (((kk << 6) + (l4 << 4)) ^ ((wc & 7) << 4));
                    uint4 uv = *reinterpret_cast<const uint4*>(Lb + byte);
                    u32 m = ok ? 0xFFFFFFFFu : 0u;
                    uv.x &= m; uv.y &= m; uv.z &= m; uv.w &= m;
                    af[nt] = *reinterpret_cast<const bf16x8*>(&uv);
                }
                const unsigned short* wb = twT + (size_t)off * 65536 + (size_t)cc * 16384
                    + (size_t)kk * 8192 + (size_t)(cobase + l15) * 32 + (l4 << 3);
                #pragma unroll
                for (int mt = 0; mt < 4; ++mt)
                    wf[mt] = *reinterpret_cast<const bf16x8*>(wb + mt * 512);   // +16 co rows
                #pragma unroll
                for (int mt = 0; mt < 4; ++mt)
                    #pragma unroll
                    for (int nt = 0; nt < 4; ++nt)
                        acc[mt][nt] = __builtin_amdgcn_mfma_f32_16x16x32_bf16(wf[mt], af[nt], acc[mt][nt], 0, 0, 0);
            }
        }
        cur ^= 1;
    }

    // ---- epilogue: direct NCHW stores ----
    float qs = fabsf(*scale);
    #pragma unroll
    for (int mt = 0; mt < 4; ++mt)
        #pragma unroll
        for (int r = 0; r < 4; ++r) {
            int co = cobase + (mt << 4) + (l4 << 2) + r;
            float bb = bias[co];
            float tv = (O == 0) ? tb[(b << 8) + co] : 0.f;
            size_t rowb = ((size_t)((b << 8) + co) << 12) + (h << 6);
            #pragma unroll
            for (int nt = 0; nt < 4; ++nt) {
                int w = (nt << 4) + l15;
                float v = __fmul_rn(acc[mt][nt][r], qs) + bb;   // fp32(I + b)
                if (O == 0) v = v + tv;                          // fp32(.. + tb)
                else        v = v + resid[rowb + w];             // fp32(.. + x)
                out[rowb + w] = v;
            }
        }
}

extern "C" void kernel_launch(void* const* d_in, const int* in_sizes, int n_in,
                              void* d_out, int out_size, void* d_ws, size_t ws_size,
                              hipStream_t stream)
{
    const float* x      = (const float*)d_in[0];
    const float* te     = (const float*)d_in[1];
    const float* gn1_g  = (const float*)d_in[2];
    const float* gn1_b  = (const float*)d_in[3];
    const float* scale1 = (const float*)d_in[4];
    const float* W1     = (const float*)d_in[5];
    const float* b1     = (const float*)d_in[6];
    const float* Wt     = (const float*)d_in[7];
    const float* bt     = (const float*)d_in[8];
    const float* gn2_g  = (const float*)d_in[9];
    const float* gn2_b  = (const float*)d_in[10];
    const float* scale2 = (const float*)d_in[11];
    const float* W2     = (const float*)d_in[12];
    const float* b2     = (const float*)d_in[13];
    float* out = (float*)d_out;

    char* ws = (char*)d_ws;
    unsigned short* a1   = (unsigned short*)(ws + WS_A1);
    unsigned short* a2   = (unsigned short*)(ws + WS_A2);
    float*          out1 = (float*)(ws + WS_OUT1);
    unsigned short* tw   = (unsigned short*)(ws + WS_TW);
    unsigned short* tw1  = tw;
    unsigned short* tw2  = tw + 589824;
    float*          tbp  = (float*)(ws + WS_TB);
    float*          gn1m = (float*)(ws + WS_GN1);
    float*          gn1r = gn1m + 256;
    float*          gn2m = (float*)(ws + WS_GN2);
    float*          gn2r = gn2m + 256;

    k_prep<<<776, 256, 0, stream>>>(x, gn1m, gn1r, W1, W2, tw, te, Wt, bt, tbp);
    k_norm_quant<<<512, 256, 0, stream>>>(x, gn1_g, gn1_b, gn1m, gn1r, scale1, a1);
    k_conv<0><<<512, 256, 0, stream>>>(a1, tw1, b1, tbp, scale1, nullptr, out1);
    k_gn_stats<<<256, 256, 0, stream>>>(out1, gn2m, gn2r);
    k_norm_quant<<<512, 256, 0, stream>>>(out1, gn2_g, gn2_b, gn2m, gn2r, scale2, a2);
    k_conv<1><<<512, 256, 0, stream>>>(a2, tw2, b2, nullptr, scale2, x, out);
}